// Round 4
// baseline (41.822 us; speedup 1.0000x reference)
//
#include <hip/hip_runtime.h>
#include <hip/hip_bf16.h>

// Problem constants (fixed by the reference: B=8, N=512, E=128, H=64)
#define BB 8
#define NN 512
#define EE 128
#define HH 64
#define EP (NN * (NN - 1))        // 261632 edges per batch
#define ECNT (BB * EP)            // 2093056 total edges
// d_out layout (floats): [edge_index row0 | edge_index row1 | edge_weights | alpha]
#define OFF_EI0 0
#define OFF_EI1 ECNT
#define OFF_EW  (2 * ECNT)
#define OFF_AL  (3 * ECNT)

// ---------------- Kernel A: projections + rank-1 terms, W staged in LDS ----------------
// pj = h@W1 + b (row-major), pkT = (h@W2)^T (h-major),
// cj[i] = 0.6*sum_h att_h*pj[i][h], dk[i] = 0.6*sum_h att_h*pk[i][h]
// block = 256 threads = 4 waves; 8 rows; wave w owns rows {row0+w, row0+w+4}
__global__ __launch_bounds__(256) void k_proj(
        const float* __restrict__ h, const float* __restrict__ W,
        const float* __restrict__ bvec, const float* __restrict__ att,
        float* __restrict__ pj, float* __restrict__ pkT,
        float* __restrict__ cj, float* __restrict__ dk) {
    __shared__ float Wl[2 * EE * HH];                // 64 KB
    const int tid = threadIdx.x;

    // stage W: 16384 floats = 4096 float4, 16 per thread, coalesced
    {
        float4* Wl4 = reinterpret_cast<float4*>(Wl);
        const float4* W4 = reinterpret_cast<const float4*>(W);
#pragma unroll
        for (int r = 0; r < 16; ++r) Wl4[r * 256 + tid] = W4[r * 256 + tid];
    }

    const int row0 = blockIdx.x * 8;
    const int c = tid & 63;                          // output column (h)
    const int w = tid >> 6;                          // wave id
    const float* hA = h + (size_t)(row0 + w) * EE;   // wave-uniform -> scalar
    const float* hB = h + (size_t)(row0 + w + 4) * EE;
    __syncthreads();

    float aj0 = 0.f, ak0 = 0.f, aj1 = 0.f, ak1 = 0.f;
#pragma unroll
    for (int e = 0; e < EE; ++e) {
        const float w1 = Wl[e * HH + c];             // stride-1 ds_read, conflict-free
        const float w2 = Wl[(EE + e) * HH + c];
        const float h0 = hA[e];
        const float h1 = hB[e];
        aj0 = fmaf(h0, w1, aj0);
        ak0 = fmaf(h0, w2, ak0);
        aj1 = fmaf(h1, w1, aj1);
        ak1 = fmaf(h1, w2, ak1);
    }
    const float bb = bvec[c];
    aj0 += bb; aj1 += bb;

    const float a6 = 0.6f * att[c];
    const int iA = row0 + w;
    const int iB = row0 + w + 4;
    pj[iA * HH + c] = aj0;
    pj[iB * HH + c] = aj1;
    {
        const int bA = iA >> 9, nA = iA & 511;
        const int bB = iB >> 9, nB = iB & 511;
        pkT[((size_t)bA * HH + c) * NN + nA] = ak0;
        pkT[((size_t)bB * HH + c) * NN + nB] = ak1;
    }
    float c0 = a6 * aj0, d0 = a6 * ak0, c1 = a6 * aj1, d1 = a6 * ak1;
#pragma unroll
    for (int off = 32; off >= 1; off >>= 1) {
        c0 += __shfl_xor(c0, off, 64);
        d0 += __shfl_xor(d0, off, 64);
        c1 += __shfl_xor(c1, off, 64);
        d1 += __shfl_xor(d1, off, 64);
    }
    if (c == 0) {
        cj[iA] = c0; dk[iA] = d0;
        cj[iB] = c1; dk[iB] = d1;
    }
}

// ---------------- Kernel B: e = cj + dk + 0.4*sum att|s|, softmax ----------------
// block = 512 threads = full k row; thread tid <-> k; 8 j rows per block
// pj rows live in LDS, read as wave-uniform float4 (HW broadcast, conflict-free)
__global__ __launch_bounds__(512, 4) void k_attn(
        const float* __restrict__ pj, const float* __restrict__ pkT,
        const float* __restrict__ att, const float* __restrict__ cj,
        const float* __restrict__ dk, float* __restrict__ alpha) {
    const int bid   = blockIdx.x;
    const int b     = bid >> 6;
    const int jbase = (bid & 63) * 8;
    const int tid   = threadIdx.x;        // = k
    const int lane  = tid & 63;
    const int wid   = tid >> 6;

    __shared__ float4 pj4[8][HH / 4];     // 2 KB
    __shared__ float  e_s[8][NN];         // 16 KB

    // stage pj: 8 rows x 16 float4 = 128 float4, coalesced
    if (tid < 128) {
        const int j = tid >> 4, q = tid & 15;
        pj4[j][q] = reinterpret_cast<const float4*>(
            pj + ((size_t)b * NN + jbase + j) * HH)[q];
    }

    // this thread's pk row (k = tid): 64 coalesced loads from pkT
    float pkr[HH];
    const float* pkb = pkT + (size_t)b * HH * NN + tid;
#pragma unroll
    for (int hh = 0; hh < HH; ++hh) pkr[hh] = pkb[hh * NN];
    const float dkv = dk[b * NN + tid];
    const float* cjb = cj + b * NN + jbase;

    __syncthreads();

    float acc[8];
#pragma unroll
    for (int j = 0; j < 8; ++j) acc[j] = 0.f;

#pragma unroll
    for (int q = 0; q < HH / 4; ++q) {
        const float4 af = reinterpret_cast<const float4*>(att)[q];  // uniform
        const float k0 = pkr[4 * q + 0];
        const float k1 = pkr[4 * q + 1];
        const float k2 = pkr[4 * q + 2];
        const float k3 = pkr[4 * q + 3];
#pragma unroll
        for (int j = 0; j < 8; ++j) {
            const float4 pw = pj4[j][q];   // wave-uniform LDS broadcast
            float s;
            s = pw.x + k0; acc[j] = fmaf(af.x, fabsf(s), acc[j]);
            s = pw.y + k1; acc[j] = fmaf(af.y, fabsf(s), acc[j]);
            s = pw.z + k2; acc[j] = fmaf(af.z, fabsf(s), acc[j]);
            s = pw.w + k3; acc[j] = fmaf(af.w, fabsf(s), acc[j]);
        }
    }

    // e rows into LDS (lane-consecutive, conflict-free)
#pragma unroll
    for (int j = 0; j < 8; ++j)
        e_s[j][tid] = fmaf(0.4f, acc[j], cjb[j] + dkv);
    __syncthreads();

    // softmax: wave wid owns row jbase+wid (512 values, 8 per lane)
    {
        float v[8];
        float m = -1e30f;
#pragma unroll
        for (int i2 = 0; i2 < 8; ++i2) {
            v[i2] = e_s[wid][lane + 64 * i2];
            m = fmaxf(m, v[i2]);
        }
#pragma unroll
        for (int off = 32; off >= 1; off >>= 1) m = fmaxf(m, __shfl_xor(m, off, 64));
        float s = 0.f;
#pragma unroll
        for (int i2 = 0; i2 < 8; ++i2) { v[i2] = __expf(v[i2] - m); s += v[i2]; }
#pragma unroll
        for (int off = 32; off >= 1; off >>= 1) s += __shfl_xor(s, off, 64);
        const float inv = 1.0f / s;
        float* arow = alpha + ((size_t)b * NN + jbase + wid) * NN;
#pragma unroll
        for (int i2 = 0; i2 < 8; ++i2) arow[lane + 64 * i2] = v[i2] * inv;
    }
}

// ---------------- Kernel C: edges, symmetric PAIR of 64x64 tiles per block ----------------
// grid = 8 b * 36 unordered tile pairs (jt<=kt); alpha read exactly once
__global__ void k_edges(const float* __restrict__ alpha, float* __restrict__ out) {
    const int bid = blockIdx.x;
    const int b   = bid / 36;
    int rem = bid - b * 36;
    int jt = 0;
    while (rem >= 8 - jt) { rem -= 8 - jt; ++jt; }   // uniform scalar loop
    const int kt = jt + rem;

    const int jbase = jt * 64;
    const int kbase = kt * 64;
    const int tid   = threadIdx.x;
    const int c     = tid & 63;
    const int r0    = tid >> 6;           // 0..3

    __shared__ float t1[64][65];          // t1[r][c] = A[jbase+r][kbase+c]
    __shared__ float t2[64][65];          // t2[r][c] = A[kbase+r][jbase+c]

    const float* A = alpha + (size_t)b * NN * NN;
    const bool diag = (jt == kt);

#pragma unroll
    for (int i = 0; i < 16; ++i) {
        const int r = i * 4 + r0;
        t1[r][c] = A[(size_t)(jbase + r) * NN + kbase + c];
    }
    if (!diag) {
#pragma unroll
        for (int i = 0; i < 16; ++i) {
            const int r = i * 4 + r0;
            t2[r][c] = A[(size_t)(kbase + r) * NN + jbase + c];
        }
    }
    __syncthreads();

    const float fb = (float)(b * NN);

    // side 1: edges (j = jbase+jj, k = kbase+c)
#pragma unroll
    for (int i = 0; i < 16; ++i) {
        const int jj = i * 4 + r0;
        const int j  = jbase + jj;
        const int k  = kbase + c;
        if (k == j) continue;             // only possible when diag
        const float a_kj = diag ? t1[c][jj] : t2[c][jj];   // padded col read, conflict-free
        const float wv = 0.5f * (t1[jj][c] + a_kj);
        const unsigned t   = (unsigned)k - ((k > j) ? 1u : 0u);
        const unsigned idx = (unsigned)b * EP + (unsigned)j * (NN - 1) + t;
        out[OFF_EI0 + idx] = fb + (float)j;
        out[OFF_EI1 + idx] = fb + (float)k;
        out[OFF_EW  + idx] = wv;
    }

    // side 2: edges (j = kbase+kk, k = jbase+c) — mirrored tile
    if (!diag) {
#pragma unroll
        for (int i = 0; i < 16; ++i) {
            const int kk = i * 4 + r0;
            const int j2 = kbase + kk;    // source node of this edge
            const int k2 = jbase + c;     // dest
            const float wv = 0.5f * (t2[kk][c] + t1[c][kk]);
            const unsigned t   = (unsigned)k2 - ((k2 > j2) ? 1u : 0u);
            const unsigned idx = (unsigned)b * EP + (unsigned)j2 * (NN - 1) + t;
            out[OFF_EI0 + idx] = fb + (float)j2;
            out[OFF_EI1 + idx] = fb + (float)k2;
            out[OFF_EW  + idx] = wv;
        }
    }
}

extern "C" void kernel_launch(void* const* d_in, const int* in_sizes, int n_in,
                              void* d_out, int out_size, void* d_ws, size_t ws_size,
                              hipStream_t stream) {
    const float* h    = (const float*)d_in[0];
    const float* W    = (const float*)d_in[1];
    const float* bvec = (const float*)d_in[2];
    const float* att  = (const float*)d_in[3];
    float* out = (float*)d_out;

    float* pj  = (float*)d_ws;                       // 1 MB
    float* pkT = pj + (size_t)BB * NN * HH;          // 1 MB, h-major
    float* cj  = pkT + (size_t)BB * NN * HH;         // 16 KB
    float* dk  = cj + BB * NN;                       // 16 KB

    float* alpha = out + OFF_AL;

    k_proj <<<BB * NN / 8, 256, 0, stream>>>(h, W, bvec, att, pj, pkT, cj, dk);
    k_attn <<<BB * 64, 512, 0, stream>>>(pj, pkT, att, cj, dk, alpha);
    k_edges<<<BB * 36, 256, 0, stream>>>(alpha, out);
}

// Round 5
// 40.886 us; speedup vs baseline: 1.0229x; 1.0229x over previous
//
#include <hip/hip_runtime.h>
#include <hip/hip_bf16.h>

// Problem constants (fixed by the reference: B=8, N=512, E=128, H=64)
#define BB 8
#define NN 512
#define EE 128
#define HH 64
#define EP (NN * (NN - 1))        // 261632 edges per batch
#define ECNT (BB * EP)            // 2093056 total edges
// d_out layout (floats): [edge_index row0 | edge_index row1 | edge_weights | alpha]
#define OFF_EI0 0
#define OFF_EI1 ECNT
#define OFF_EW  (2 * ECNT)
#define OFF_AL  (3 * ECNT)

// ---------------- Kernel A: projections + rank-1 terms, W staged in LDS ----------------
// pj = h@W1 + b (row-major), pkT4 = (h@W2)^T in h-interleaved float4 layout:
//   pkT4[(b*16 + h/4)*NN + n] = float4(pk[b][n][4(h/4)..4(h/4)+3])
// cj[i] = 0.6*sum_h att_h*pj[i][h], dk[i] = 0.6*sum_h att_h*pk[i][h]
// block = 256 threads = 4 waves; 8 rows; wave w owns rows {row0+w, row0+w+4}
__global__ __launch_bounds__(256) void k_proj(
        const float* __restrict__ h, const float* __restrict__ W,
        const float* __restrict__ bvec, const float* __restrict__ att,
        float* __restrict__ pj, float* __restrict__ pkT4f,
        float* __restrict__ cj, float* __restrict__ dk) {
    __shared__ float Wl[2 * EE * HH];                // 64 KB
    const int tid = threadIdx.x;

    // stage W: 16384 floats = 4096 float4, 16 per thread, coalesced
    {
        float4* Wl4 = reinterpret_cast<float4*>(Wl);
        const float4* W4 = reinterpret_cast<const float4*>(W);
#pragma unroll
        for (int r = 0; r < 16; ++r) Wl4[r * 256 + tid] = W4[r * 256 + tid];
    }

    const int row0 = blockIdx.x * 8;
    const int c = tid & 63;                          // output column (h)
    const int w = tid >> 6;                          // wave id
    const float* hA = h + (size_t)(row0 + w) * EE;   // wave-uniform -> scalar loads
    const float* hB = h + (size_t)(row0 + w + 4) * EE;
    __syncthreads();

    float aj0 = 0.f, ak0 = 0.f, aj1 = 0.f, ak1 = 0.f;
#pragma unroll
    for (int e = 0; e < EE; ++e) {
        const float w1 = Wl[e * HH + c];             // stride-1 ds_read, conflict-free
        const float w2 = Wl[(EE + e) * HH + c];
        const float h0 = hA[e];
        const float h1 = hB[e];
        aj0 = fmaf(h0, w1, aj0);
        ak0 = fmaf(h0, w2, ak0);
        aj1 = fmaf(h1, w1, aj1);
        ak1 = fmaf(h1, w2, ak1);
    }
    const float bb = bvec[c];
    aj0 += bb; aj1 += bb;

    const float a6 = 0.6f * att[c];
    const int iA = row0 + w;
    const int iB = row0 + w + 4;
    pj[iA * HH + c] = aj0;
    pj[iB * HH + c] = aj1;
    {
        const int bA = iA >> 9, nA = iA & 511;
        const int bB = iB >> 9, nB = iB & 511;
        // h-interleaved float4 transpose: float index = ((b*16 + c/4)*NN + n)*4 + (c&3)
        pkT4f[(((size_t)(bA * 16 + (c >> 2)) * NN + nA) << 2) + (c & 3)] = ak0;
        pkT4f[(((size_t)(bB * 16 + (c >> 2)) * NN + nB) << 2) + (c & 3)] = ak1;
    }
    float c0 = a6 * aj0, d0 = a6 * ak0, c1 = a6 * aj1, d1 = a6 * ak1;
#pragma unroll
    for (int off = 32; off >= 1; off >>= 1) {
        c0 += __shfl_xor(c0, off, 64);
        d0 += __shfl_xor(d0, off, 64);
        c1 += __shfl_xor(c1, off, 64);
        d1 += __shfl_xor(d1, off, 64);
    }
    if (c == 0) {
        cj[iA] = c0; dk[iA] = d0;
        cj[iB] = c1; dk[iB] = d1;
    }
}

// ---------------- Kernel B: e = cj + dk + 0.4*sum att|s|, softmax ----------------
// block = 512 threads = full k row; thread tid <-> k; 8 j rows per block
// launch_bounds (512,2): 256-VGPR budget -> pk payload (64 regs) stays in registers
__global__ __launch_bounds__(512, 2) void k_attn(
        const float* __restrict__ pj, const float4* __restrict__ pkT4,
        const float* __restrict__ att, const float* __restrict__ cj,
        const float* __restrict__ dk, float* __restrict__ alpha) {
    const int bid   = blockIdx.x;
    const int b     = bid >> 6;
    const int jbase = (bid & 63) * 8;
    const int tid   = threadIdx.x;        // = k
    const int lane  = tid & 63;
    const int wid   = tid >> 6;

    __shared__ float4 pj4[8][HH / 4];     // 2 KB
    __shared__ float  e_s[8][NN];         // 16 KB

    // stage pj: 8 rows x 16 float4 = 128 float4, coalesced
    if (tid < 128) {
        const int j = tid >> 4, q = tid & 15;
        pj4[j][q] = reinterpret_cast<const float4*>(
            pj + ((size_t)b * NN + jbase + j) * HH)[q];
    }

    // this thread's pk row (k = tid): 16 coalesced dwordx4 loads
    float4 pk4[16];
    const float4* pkb = pkT4 + (size_t)b * 16 * NN + tid;
#pragma unroll
    for (int q = 0; q < 16; ++q) pk4[q] = pkb[q * NN];
    const float dkv = dk[b * NN + tid];
    const float* cjb = cj + b * NN + jbase;

    __syncthreads();

    float acc[8];
#pragma unroll
    for (int j = 0; j < 8; ++j) acc[j] = 0.f;

#pragma unroll
    for (int q = 0; q < 16; ++q) {
        const float4 af = reinterpret_cast<const float4*>(att)[q];  // uniform
        const float4 kv = pk4[q];
#pragma unroll
        for (int j = 0; j < 8; ++j) {
            const float4 pw = pj4[j][q];   // wave-uniform LDS broadcast
            float s;
            s = pw.x + kv.x; acc[j] = fmaf(af.x, fabsf(s), acc[j]);
            s = pw.y + kv.y; acc[j] = fmaf(af.y, fabsf(s), acc[j]);
            s = pw.z + kv.z; acc[j] = fmaf(af.z, fabsf(s), acc[j]);
            s = pw.w + kv.w; acc[j] = fmaf(af.w, fabsf(s), acc[j]);
        }
    }

    // e rows into LDS (lane-consecutive, conflict-free)
#pragma unroll
    for (int j = 0; j < 8; ++j)
        e_s[j][tid] = fmaf(0.4f, acc[j], cjb[j] + dkv);
    __syncthreads();

    // softmax: wave wid owns row jbase+wid (512 values, 8 per lane)
    {
        float v[8];
        float m = -1e30f;
#pragma unroll
        for (int i2 = 0; i2 < 8; ++i2) {
            v[i2] = e_s[wid][lane + 64 * i2];
            m = fmaxf(m, v[i2]);
        }
#pragma unroll
        for (int off = 32; off >= 1; off >>= 1) m = fmaxf(m, __shfl_xor(m, off, 64));
        float s = 0.f;
#pragma unroll
        for (int i2 = 0; i2 < 8; ++i2) { v[i2] = __expf(v[i2] - m); s += v[i2]; }
#pragma unroll
        for (int off = 32; off >= 1; off >>= 1) s += __shfl_xor(s, off, 64);
        const float inv = 1.0f / s;
        float* arow = alpha + ((size_t)b * NN + jbase + wid) * NN;
#pragma unroll
        for (int i2 = 0; i2 < 8; ++i2) arow[lane + 64 * i2] = v[i2] * inv;
    }
}

// ---------------- Kernel C: edges, symmetric PAIR of 64x64 tiles per block ----------------
// grid = 8 b * 36 unordered tile pairs (jt<=kt); alpha read exactly once
__global__ void k_edges(const float* __restrict__ alpha, float* __restrict__ out) {
    const int bid = blockIdx.x;
    const int b   = bid / 36;
    int rem = bid - b * 36;
    int jt = 0;
    while (rem >= 8 - jt) { rem -= 8 - jt; ++jt; }   // uniform scalar loop
    const int kt = jt + rem;

    const int jbase = jt * 64;
    const int kbase = kt * 64;
    const int tid   = threadIdx.x;
    const int c     = tid & 63;
    const int r0    = tid >> 6;           // 0..3

    __shared__ float t1[64][65];          // t1[r][c] = A[jbase+r][kbase+c]
    __shared__ float t2[64][65];          // t2[r][c] = A[kbase+r][jbase+c]

    const float* A = alpha + (size_t)b * NN * NN;
    const bool diag = (jt == kt);

#pragma unroll
    for (int i = 0; i < 16; ++i) {
        const int r = i * 4 + r0;
        t1[r][c] = A[(size_t)(jbase + r) * NN + kbase + c];
    }
    if (!diag) {
#pragma unroll
        for (int i = 0; i < 16; ++i) {
            const int r = i * 4 + r0;
            t2[r][c] = A[(size_t)(kbase + r) * NN + jbase + c];
        }
    }
    __syncthreads();

    const float fb = (float)(b * NN);

    // side 1: edges (j = jbase+jj, k = kbase+c)
#pragma unroll
    for (int i = 0; i < 16; ++i) {
        const int jj = i * 4 + r0;
        const int j  = jbase + jj;
        const int k  = kbase + c;
        if (k == j) continue;             // only possible when diag
        const float a_kj = diag ? t1[c][jj] : t2[c][jj];   // padded col read
        const float wv = 0.5f * (t1[jj][c] + a_kj);
        const unsigned t   = (unsigned)k - ((k > j) ? 1u : 0u);
        const unsigned idx = (unsigned)b * EP + (unsigned)j * (NN - 1) + t;
        out[OFF_EI0 + idx] = fb + (float)j;
        out[OFF_EI1 + idx] = fb + (float)k;
        out[OFF_EW  + idx] = wv;
    }

    // side 2: edges (j = kbase+kk, k = jbase+c) — mirrored tile
    if (!diag) {
#pragma unroll
        for (int i = 0; i < 16; ++i) {
            const int kk = i * 4 + r0;
            const int j2 = kbase + kk;
            const int k2 = jbase + c;
            const float wv = 0.5f * (t2[kk][c] + t1[c][kk]);
            const unsigned t   = (unsigned)k2 - ((k2 > j2) ? 1u : 0u);
            const unsigned idx = (unsigned)b * EP + (unsigned)j2 * (NN - 1) + t;
            out[OFF_EI0 + idx] = fb + (float)j2;
            out[OFF_EI1 + idx] = fb + (float)k2;
            out[OFF_EW  + idx] = wv;
        }
    }
}

extern "C" void kernel_launch(void* const* d_in, const int* in_sizes, int n_in,
                              void* d_out, int out_size, void* d_ws, size_t ws_size,
                              hipStream_t stream) {
    const float* h    = (const float*)d_in[0];
    const float* W    = (const float*)d_in[1];
    const float* bvec = (const float*)d_in[2];
    const float* att  = (const float*)d_in[3];
    float* out = (float*)d_out;

    float* pj   = (float*)d_ws;                      // 1 MB
    float* pkT4 = pj + (size_t)BB * NN * HH;         // 1 MB, h-interleaved float4
    float* cj   = pkT4 + (size_t)BB * NN * HH;       // 16 KB
    float* dk   = cj + BB * NN;                      // 16 KB

    float* alpha = out + OFF_AL;

    k_proj <<<BB * NN / 8, 256, 0, stream>>>(h, W, bvec, att, pj, pkT4, cj, dk);
    k_attn <<<BB * 64, 512, 0, stream>>>(pj, (const float4*)pkT4, att, cj, dk, alpha);
    k_edges<<<BB * 36, 256, 0, stream>>>(alpha, out);
}